// Round 7
// baseline (156.332 us; speedup 1.0000x reference)
//
#include <hip/hip_runtime.h>

typedef __bf16 bf16;
typedef __attribute__((ext_vector_type(8))) __bf16 bf16x8;
typedef __attribute__((ext_vector_type(4))) __bf16 bf16x4;
typedef __attribute__((ext_vector_type(2))) __bf16 bf16x2;
typedef __attribute__((ext_vector_type(4))) float f32x4;
typedef __attribute__((ext_vector_type(16))) float f32x16;

// sizes: B=8, S=1024, F=512, H=8, DK=64, T = 1024-201 = 823
// Q is pre-scaled by 0.125*log2(e) -> scores are in log2 units; softmax uses raw exp2 (no max:
// LN-bounded scores can't overflow f32 exp2, and softmax is shift-invariant).
#define QSCL 0.18033688011112042f

__device__ __forceinline__ void gload16(const void* g, void* l) {
  __builtin_amdgcn_global_load_lds(
      (const __attribute__((address_space(1))) void*)g,
      (__attribute__((address_space(3))) void*)l, 16, 0, 0);
}

__device__ __forceinline__ unsigned pack2bf(float a, float b) {
  union { bf16x2 v; unsigned u; } t;
  t.v[0] = (bf16)a; t.v[1] = (bf16)b;
  return t.u;
}
__device__ __forceinline__ float bperm_f(int byteaddr, float v) {
  return __int_as_float(__builtin_amdgcn_ds_bpermute(byteaddr, __float_as_int(v)));
}

// ---------------- prep: weight packs (blocks 0..1023) + layernorm (blocks 1024..3071) ----------------
__global__ __launch_bounds__(256) void prep_kernel(
    const float* __restrict__ x, const float* __restrict__ gam, const float* __restrict__ bet,
    const float* __restrict__ WQ, const float* __restrict__ WK,
    const float* __restrict__ WV, const float* __restrict__ WO,
    bf16* __restrict__ xn, bf16* __restrict__ Bt, bf16* __restrict__ WOt) {
  __shared__ float t[32][33];
  const int tid = threadIdx.x;
  const int bid = blockIdx.x;
  if (bid < 1024) {
    const int tx = tid & 31, ty = tid >> 5;
    if (bid < 768) {
      const int g = bid >> 5, rem = bid & 31;
      const int db = rem >> 4, kb = rem & 15;
      const int mat = g >> 3, h = g & 7;
      const float* W = (mat == 0) ? WQ : ((mat == 1) ? WK : WV);
      #pragma unroll
      for (int r = 0; r < 4; ++r) {
        const int kloc = r * 8 + ty;
        t[kloc][tx] = W[((size_t)h * 512 + kb * 32 + kloc) * 64 + db * 32 + tx];
      }
      __syncthreads();
      #pragma unroll
      for (int r = 0; r < 4; ++r) {
        const int dloc = r * 8 + ty;
        Bt[((size_t)mat * 512 + h * 64 + db * 32 + dloc) * 512 + kb * 32 + tx] = (bf16)t[tx][dloc];
      }
    } else {
      const int bid2 = bid - 768;
      const int nb = bid2 >> 4, kb = bid2 & 15;
      #pragma unroll
      for (int r = 0; r < 4; ++r) {
        const int kloc = r * 8 + ty;
        t[kloc][tx] = WO[((size_t)kb * 32 + kloc) * 512 + nb * 32 + tx];
      }
      __syncthreads();
      #pragma unroll
      for (int r = 0; r < 4; ++r) {
        const int nloc = r * 8 + ty;
        WOt[((size_t)nb * 32 + nloc) * 512 + kb * 32 + tx] = (bf16)t[tx][nloc];
      }
    }
  } else {
    const int wave = tid >> 6, lane = tid & 63;
    const int row = (bid - 1024) * 4 + wave;
    const float4* xr = (const float4*)(x + (size_t)row * 512);
    float4 v0 = xr[lane], v1 = xr[lane + 64];
    float s  = v0.x + v0.y + v0.z + v0.w + v1.x + v1.y + v1.z + v1.w;
    float s2 = v0.x * v0.x + v0.y * v0.y + v0.z * v0.z + v0.w * v0.w
             + v1.x * v1.x + v1.y * v1.y + v1.z * v1.z + v1.w * v1.w;
    #pragma unroll
    for (int m = 1; m < 64; m <<= 1) { s += __shfl_xor(s, m); s2 += __shfl_xor(s2, m); }
    const float mu = s * (1.f / 512.f);
    const float rstd = rsqrtf(s2 * (1.f / 512.f) - mu * mu + 1e-5f);
    const float4* gr = (const float4*)gam;
    const float4* br = (const float4*)bet;
    float4 g0 = gr[lane], g1 = gr[lane + 64], b0 = br[lane], b1 = br[lane + 64];
    bf16x4 o0, o1;
    o0[0] = (bf16)((v0.x - mu) * rstd * g0.x + b0.x);
    o0[1] = (bf16)((v0.y - mu) * rstd * g0.y + b0.y);
    o0[2] = (bf16)((v0.z - mu) * rstd * g0.z + b0.z);
    o0[3] = (bf16)((v0.w - mu) * rstd * g0.w + b0.w);
    o1[0] = (bf16)((v1.x - mu) * rstd * g1.x + b1.x);
    o1[1] = (bf16)((v1.y - mu) * rstd * g1.y + b1.y);
    o1[2] = (bf16)((v1.z - mu) * rstd * g1.z + b1.z);
    o1[3] = (bf16)((v1.w - mu) * rstd * g1.w + b1.w);
    *(bf16x4*)(xn + (size_t)row * 512 + lane * 4) = o0;
    *(bf16x4*)(xn + (size_t)row * 512 + 256 + lane * 4) = o1;
  }
}

// ---------------- GEMM: C[M][N] = A[M][512] * Bt[N][512]^T, 128x128 tile, BK=64, 4 waves ----------------
// 2-buffer LDS, counted vmcnt(8): per step t -> [barrier; STAGE(t+1); vmcnt(8) (=stage(t) landed);
// barrier; 32 MFMA from buf t&1]. Stage latency hides under a full step's compute.
// LDS tiles XOR-swizzled: read byte ^= ((row&7)<<4); inverse applied on GLOBAL source address
// (global_load_lds writes linearly) -> ds_read_b128 is 2-way (free) instead of 16-way.
// MODE 0: QKV epilogue (Q scaled by QSCL; V transposed via swizzled LDS tile -> coalesced stores)
// MODE 1: output projection epilogue (bias + f32 out)
template <int MODE>
__global__ __launch_bounds__(256) void gemm_kernel(
    const bf16* __restrict__ A, const bf16* __restrict__ Bt, float* __restrict__ outF,
    bf16* __restrict__ qb, bf16* __restrict__ kb, bf16* __restrict__ vtb,
    const float* __restrict__ biasQ, const float* __restrict__ biasK,
    const float* __restrict__ biasV, const float* __restrict__ biasO) {
  __shared__ __align__(16) bf16 sA[2][8192];   // [buf][128 rows][64 cols], swizzled
  __shared__ __align__(16) bf16 sB[2][8192];
  const int tid = threadIdx.x;
  const int wave = tid >> 6, lane = tid & 63;
  const int m0 = blockIdx.x * 128, n0 = blockIdx.y * 128;
  const int wm = (wave >> 1) * 64, wn = (wave & 1) * 64;
  const int lrow = lane & 15, lg = lane >> 4;
  // staging geometry: chunk ch covers rows [ch*8, ch*8+8) of the 128x64 tile; lane -> row ch*8+(lane>>3),
  // dest inner byte (lane&7)*16; source col pre-swizzled: elements 8*((lane&7)^(lane>>3))
  const int strow = lane >> 3;
  const int stcol = 8 * ((lane & 7) ^ strow);
  f32x4 acc[4][4] = {};
  auto STAGE = [&](int kt, int buf) {
    #pragma unroll
    for (int c = 0; c < 4; ++c) {
      const int ch = wave * 4 + c;
      gload16(A + (size_t)(m0 + ch * 8 + strow) * 512 + kt + stcol, &sA[buf][ch * 512]);
      gload16(Bt + (size_t)(n0 + ch * 8 + strow) * 512 + kt + stcol, &sB[buf][ch * 512]);
    }
  };
  STAGE(0, 0);
  const int rsw = (lrow & 7) << 4;  // read swizzle (row&7 == lrow&7 for all fragment rows)
  #pragma unroll
  for (int t = 0; t < 8; ++t) {
    __builtin_amdgcn_s_barrier();            // separates compute(t-1) reads from stage(t+1) writes
    asm volatile("" ::: "memory");
    if (t < 7) STAGE((t + 1) * 64, (t + 1) & 1);
    if (t < 7) asm volatile("s_waitcnt vmcnt(8)" ::: "memory");
    else       asm volatile("s_waitcnt vmcnt(0)" ::: "memory");
    __builtin_amdgcn_s_barrier();            // stage(t) visible to all waves
    asm volatile("" ::: "memory");
    const int buf = t & 1;
    #pragma unroll
    for (int kk = 0; kk < 2; ++kk) {
      bf16x8 af[4], bfr[4];
      #pragma unroll
      for (int mi = 0; mi < 4; ++mi)
        af[mi] = *(const bf16x8*)((const char*)sA[buf] + (wm + mi * 16 + lrow) * 128 +
                                  ((kk * 64 + lg * 16) ^ rsw));
      #pragma unroll
      for (int ni = 0; ni < 4; ++ni)
        bfr[ni] = *(const bf16x8*)((const char*)sB[buf] + (wn + ni * 16 + lrow) * 128 +
                                   ((kk * 64 + lg * 16) ^ rsw));
      __builtin_amdgcn_s_setprio(1);
      #pragma unroll
      for (int mi = 0; mi < 4; ++mi)
        #pragma unroll
        for (int ni = 0; ni < 4; ++ni)
          acc[mi][ni] = __builtin_amdgcn_mfma_f32_16x16x32_bf16(af[mi], bfr[ni], acc[mi][ni], 0, 0, 0);
      __builtin_amdgcn_s_setprio(0);
    }
  }
  if (MODE == 0) {
    const int yy = blockIdx.y;
    if (yy < 8) {
      const bool isQ = (yy < 4);
      bf16* dst = isQ ? qb : kb;
      const float* bias = isQ ? biasQ : biasK;
      #pragma unroll
      for (int ni = 0; ni < 4; ++ni) {
        const int n = n0 + wn + ni * 16 + lrow;
        const int rem = n & 511;
        const int hh = rem >> 6, d = rem & 63;
        const float bv = bias[rem];
        #pragma unroll
        for (int mi = 0; mi < 4; ++mi) {
          #pragma unroll
          for (int r = 0; r < 4; ++r) {
            const int m = m0 + wm + mi * 16 + lg * 4 + r;
            const int bb = m >> 10, ss = m & 1023;
            float val = acc[mi][ni][r] + bv;
            if (isQ) val *= QSCL;
            dst[(((size_t)bb * 8 + hh) * 1024 + ss) * 64 + d] = (bf16)val;
          }
        }
      }
    } else {
      // V: transpose through swizzled LDS tile (reuses sA), then coalesced 16B stores
      const int rem0 = n0 - 1024;
      const int bb = m0 >> 10, ss0 = m0 & 1023;
      char* tbuf = (char*)sA;
      __syncthreads();
      #pragma unroll
      for (int ni = 0; ni < 4; ++ni) {
        const int n_loc = wn + ni * 16 + lrow;
        const float bv = biasV[rem0 + n_loc];
        #pragma unroll
        for (int mi = 0; mi < 4; ++mi) {
          #pragma unroll
          for (int r = 0; r < 4; ++r) {
            const int m_loc = wm + mi * 16 + lg * 4 + r;
            *(bf16*)(tbuf + n_loc * 256 + ((m_loc * 2) ^ ((n_loc & 15) << 4))) =
                (bf16)(acc[mi][ni][r] + bv);
          }
        }
      }
      __syncthreads();
      const int rr = tid >> 4, kk = tid & 15;
      #pragma unroll
      for (int p = 0; p < 8; ++p) {
        const int r = p * 16 + rr;
        const bf16x8 vv = *(const bf16x8*)(tbuf + r * 256 + ((kk * 16) ^ ((r & 15) << 4)));
        *(bf16x8*)(vtb + (size_t)bb * 524288 + (size_t)(rem0 + r) * 1024 + ss0 + kk * 8) = vv;
      }
    }
  } else {
    #pragma unroll
    for (int ni = 0; ni < 4; ++ni) {
      const int n = n0 + wn + ni * 16 + lrow;
      const float bias = biasO[n];
      #pragma unroll
      for (int mi = 0; mi < 4; ++mi) {
        #pragma unroll
        for (int r = 0; r < 4; ++r) {
          const int m = m0 + wm + mi * 16 + lg * 4 + r;
          outF[(size_t)m * 512 + n] = acc[mi][ni][r] + bias;
        }
      }
    }
  }
}

// ---------------- flash attention: swapped-QK 32x32 MFMA, static-offset softmax ----------------
__global__ __launch_bounds__(256, 2) void attn_kernel(
    const bf16* __restrict__ qbuf, const bf16* __restrict__ kbuf,
    const bf16* __restrict__ vtbuf, bf16* __restrict__ z) {
  __shared__ __align__(16) char sK[2][8192];
  __shared__ __align__(16) char sV[2][8192];
  const int tid = threadIdx.x;
  const int wave = tid >> 6, lane = tid & 63;
  const int bh = blockIdx.x;
  const int b = bh >> 3, h = bh & 7;
  const int y = blockIdx.y;
  const int q0 = y * 128 + wave * 32;
  const int ql = lane & 31, hf = lane >> 5;
  const bf16* Q  = qbuf  + (size_t)bh * 65536;
  const bf16* K  = kbuf  + (size_t)bh * 65536;
  const bf16* Vt = vtbuf + (size_t)bh * 65536;

  bf16x8 qf[4];
  #pragma unroll
  for (int s = 0; s < 4; ++s)
    qf[s] = *(const bf16x8*)(Q + (size_t)(q0 + ql) * 64 + s * 16 + hf * 8);

  int kOff[2], vOff[2], dstO[2];
  #pragma unroll
  for (int cc = 0; cc < 2; ++cc) {
    const int p = wave * 1024 + cc * 4096 + lane * 16;
    const int row = p >> 8, inner = p & 255;
    const int inn = inner ^ ((row & 15) << 4);
    const int src_row = row + (inn >> 7) * 32;
    const int colb = inn & 127;
    kOff[cc] = src_row * 128 + colb;
    vOff[cc] = src_row * 2048 + colb;
    dstO[cc] = wave * 1024 + cc * 4096;
  }
  const int hs = (hf * 16) ^ ((ql & 15) << 4);
  const int rbase = ql * 256;
  const int iq = q0 + ql;
  const int thr = (iq < 823) ? 823 : ((iq == 1023) ? 1024 : iq);

  float lsum = 0.f;
  f32x16 og[2] = {};
  const int ntile = (y == 7) ? 16 : ((y == 6) ? 14 : 13);

  #pragma unroll
  for (int cc = 0; cc < 2; ++cc) {
    gload16((const char*)K + kOff[cc], sK[0] + dstO[cc]);
    gload16((const char*)Vt + vOff[cc], sV[0] + dstO[cc]);
  }
  __syncthreads();

  for (int jt = 0; jt < ntile; ++jt) {
    const int j0 = jt * 64;
    const int cur = jt & 1;
    if (jt + 1 < ntile) {
      #pragma unroll
      for (int cc = 0; cc < 2; ++cc) {
        gload16((const char*)K + (size_t)(j0 + 64) * 128 + kOff[cc], sK[cur ^ 1] + dstO[cc]);
        gload16((const char*)Vt + (size_t)(j0 + 64) * 2 + vOff[cc], sV[cur ^ 1] + dstO[cc]);
      }
    }
    f32x16 st[2] = {};
    __builtin_amdgcn_s_setprio(1);
    #pragma unroll
    for (int bb = 0; bb < 2; ++bb)
      #pragma unroll
      for (int s = 0; s < 4; ++s) {
        const bf16x8 kf = *(const bf16x8*)(sK[cur] + rbase + ((bb * 128 + s * 32) ^ hs));
        st[bb] = __builtin_amdgcn_mfma_f32_32x32x16_bf16(kf, qf[s], st[bb], 0, 0, 0);
      }
    __builtin_amdgcn_s_setprio(0);
    if (j0 + 63 >= 823) {
      #pragma unroll
      for (int bb = 0; bb < 2; ++bb)
        #pragma unroll
        for (int rg = 0; rg < 16; ++rg) {
          const int kv = j0 + bb * 32 + (rg & 3) + 8 * (rg >> 2) + 4 * hf;
          if (kv >= thr) st[bb][rg] = -1e9f;
        }
    }
    unsigned pk[2][8];
    float ps = 0.f;
    #pragma unroll
    for (int bb = 0; bb < 2; ++bb)
      #pragma unroll
      for (int c = 0; c < 4; ++c) {
        const float p0 = exp2f(st[bb][4 * c + 0]);
        const float p1 = exp2f(st[bb][4 * c + 1]);
        const float p2 = exp2f(st[bb][4 * c + 2]);
        const float p3 = exp2f(st[bb][4 * c + 3]);
        ps += (p0 + p1) + (p2 + p3);
        pk[bb][c * 2 + 0] = pack2bf(p0, p1);
        pk[bb][c * 2 + 1] = pack2bf(p2, p3);
      }
    lsum += ps;
    unsigned sw[2][8];
    #pragma unroll
    for (int bb = 0; bb < 2; ++bb)
      #pragma unroll
      for (int w = 0; w < 8; ++w) sw[bb][w] = __shfl_xor(pk[bb][w], 32);
    __builtin_amdgcn_s_setprio(1);
    #pragma unroll
    for (int bb = 0; bb < 2; ++bb)
      #pragma unroll
      for (int tt = 0; tt < 2; ++tt) {
        union { unsigned u[4]; bf16x8 v; } fr;
        fr.u[0] = hf ? sw[bb][(2 * tt + 1) * 2 + 0] : pk[bb][(2 * tt) * 2 + 0];
        fr.u[1] = hf ? sw[bb][(2 * tt + 1) * 2 + 1] : pk[bb][(2 * tt) * 2 + 1];
        fr.u[2] = hf ? pk[bb][(2 * tt + 1) * 2 + 0] : sw[bb][(2 * tt) * 2 + 0];
        fr.u[3] = hf ? pk[bb][(2 * tt + 1) * 2 + 1] : sw[bb][(2 * tt) * 2 + 1];
        const int step = bb * 2 + tt;
        #pragma unroll
        for (int g = 0; g < 2; ++g) {
          const bf16x8 vf = *(const bf16x8*)(sV[cur] + rbase + ((g * 128 + step * 32) ^ hs));
          og[g] = __builtin_amdgcn_mfma_f32_32x32x16_bf16(fr.v, vf, og[g], 0, 0, 0);
        }
      }
    __builtin_amdgcn_s_setprio(0);
    __syncthreads();
  }
  lsum += __shfl_xor(lsum, 32);
  const float inv = 1.f / lsum;
  #pragma unroll
  for (int rg = 0; rg < 16; ++rg) {
    const int rowq = (rg & 3) + 8 * (rg >> 2) + 4 * hf;
    const float oinv = bperm_f(rowq << 2, inv);
    const int q_abs = q0 + rowq;
    #pragma unroll
    for (int g = 0; g < 2; ++g)
      z[((size_t)b * 1024 + q_abs) * 512 + h * 64 + g * 32 + ql] = (bf16)(og[g][rg] * oinv);
  }
}

extern "C" void kernel_launch(void* const* d_in, const int* in_sizes, int n_in,
                              void* d_out, int out_size, void* d_ws, size_t ws_size,
                              hipStream_t stream) {
  const float* x  = (const float*)d_in[0];
  const float* g  = (const float*)d_in[1];
  const float* be = (const float*)d_in[2];
  const float* WQ = (const float*)d_in[3];
  const float* bq = (const float*)d_in[4];
  const float* WK = (const float*)d_in[5];
  const float* bk = (const float*)d_in[6];
  const float* WV = (const float*)d_in[7];
  const float* bv = (const float*)d_in[8];
  const float* WO = (const float*)d_in[9];
  const float* bO = (const float*)d_in[10];
  float* out = (float*)d_out;
  char* ws = (char*)d_ws;
  bf16* xn  = (bf16*)(ws);              // [8192][512] LN output, later reused as z
  bf16* Bt  = (bf16*)(ws + 8388608);    // [1536][512] packed QKV weights^T
  bf16* WOt = (bf16*)(ws + 9961472);    // [512][512]  WO^T
  bf16* qb  = (bf16*)(ws + 10485760);   // [8][8][1024][64]
  bf16* kb  = (bf16*)(ws + 18874368);   // [8][8][1024][64]
  bf16* vtb = (bf16*)(ws + 27262976);   // [8][8][64][1024]
  prep_kernel<<<3072, 256, 0, stream>>>(x, g, be, WQ, WK, WV, WO, xn, Bt, WOt);
  gemm_kernel<0><<<dim3(64, 12), 256, 0, stream>>>(xn, Bt, nullptr, qb, kb, vtb, bq, bk, bv, nullptr);
  attn_kernel<<<dim3(64, 8), 256, 0, stream>>>(qb, kb, vtb, xn /* reuse as z */);
  gemm_kernel<1><<<dim3(64, 4), 256, 0, stream>>>(xn, WOt, out, nullptr, nullptr, nullptr,
                                                  nullptr, nullptr, nullptr, bO);
}

// Round 8
// 151.373 us; speedup vs baseline: 1.0328x; 1.0328x over previous
//
#include <hip/hip_runtime.h>

typedef __bf16 bf16;
typedef __attribute__((ext_vector_type(8))) __bf16 bf16x8;
typedef __attribute__((ext_vector_type(4))) __bf16 bf16x4;
typedef __attribute__((ext_vector_type(2))) __bf16 bf16x2;
typedef __attribute__((ext_vector_type(4))) float f32x4;
typedef __attribute__((ext_vector_type(16))) float f32x16;

// sizes: B=8, S=1024, F=512, H=8, DK=64, T = 1024-201 = 823
// Q is pre-scaled by 0.125*log2(e) -> scores in log2 units; raw exp2 softmax (shift-invariant,
// LN-bounded scores can't overflow f32).
#define QSCL 0.18033688011112042f

__device__ __forceinline__ void gload16(const void* g, void* l) {
  __builtin_amdgcn_global_load_lds(
      (const __attribute__((address_space(1))) void*)g,
      (__attribute__((address_space(3))) void*)l, 16, 0, 0);
}

__device__ __forceinline__ unsigned pack2bf(float a, float b) {
  union { bf16x2 v; unsigned u; } t;
  t.v[0] = (bf16)a; t.v[1] = (bf16)b;
  return t.u;
}
__device__ __forceinline__ float bperm_f(int byteaddr, float v) {
  return __int_as_float(__builtin_amdgcn_ds_bpermute(byteaddr, __float_as_int(v)));
}

// ---------------- prep: weight packs (blocks 0..1023) + layernorm (blocks 1024..3071) ----------------
__global__ __launch_bounds__(256) void prep_kernel(
    const float* __restrict__ x, const float* __restrict__ gam, const float* __restrict__ bet,
    const float* __restrict__ WQ, const float* __restrict__ WK,
    const float* __restrict__ WV, const float* __restrict__ WO,
    bf16* __restrict__ xn, bf16* __restrict__ Bt, bf16* __restrict__ WOt) {
  __shared__ float t[32][33];
  const int tid = threadIdx.x;
  const int bid = blockIdx.x;
  if (bid < 1024) {
    const int tx = tid & 31, ty = tid >> 5;
    if (bid < 768) {
      const int g = bid >> 5, rem = bid & 31;
      const int db = rem >> 4, kb = rem & 15;
      const int mat = g >> 3, h = g & 7;
      const float* W = (mat == 0) ? WQ : ((mat == 1) ? WK : WV);
      #pragma unroll
      for (int r = 0; r < 4; ++r) {
        const int kloc = r * 8 + ty;
        t[kloc][tx] = W[((size_t)h * 512 + kb * 32 + kloc) * 64 + db * 32 + tx];
      }
      __syncthreads();
      #pragma unroll
      for (int r = 0; r < 4; ++r) {
        const int dloc = r * 8 + ty;
        Bt[((size_t)mat * 512 + h * 64 + db * 32 + dloc) * 512 + kb * 32 + tx] = (bf16)t[tx][dloc];
      }
    } else {
      const int bid2 = bid - 768;
      const int nb = bid2 >> 4, kb = bid2 & 15;
      #pragma unroll
      for (int r = 0; r < 4; ++r) {
        const int kloc = r * 8 + ty;
        t[kloc][tx] = WO[((size_t)kb * 32 + kloc) * 512 + nb * 32 + tx];
      }
      __syncthreads();
      #pragma unroll
      for (int r = 0; r < 4; ++r) {
        const int nloc = r * 8 + ty;
        WOt[((size_t)nb * 32 + nloc) * 512 + kb * 32 + tx] = (bf16)t[tx][nloc];
      }
    }
  } else {
    const int wave = tid >> 6, lane = tid & 63;
    const int row = (bid - 1024) * 4 + wave;
    const float4* xr = (const float4*)(x + (size_t)row * 512);
    float4 v0 = xr[lane], v1 = xr[lane + 64];
    float s  = v0.x + v0.y + v0.z + v0.w + v1.x + v1.y + v1.z + v1.w;
    float s2 = v0.x * v0.x + v0.y * v0.y + v0.z * v0.z + v0.w * v0.w
             + v1.x * v1.x + v1.y * v1.y + v1.z * v1.z + v1.w * v1.w;
    #pragma unroll
    for (int m = 1; m < 64; m <<= 1) { s += __shfl_xor(s, m); s2 += __shfl_xor(s2, m); }
    const float mu = s * (1.f / 512.f);
    const float rstd = rsqrtf(s2 * (1.f / 512.f) - mu * mu + 1e-5f);
    const float4* gr = (const float4*)gam;
    const float4* br = (const float4*)bet;
    float4 g0 = gr[lane], g1 = gr[lane + 64], b0 = br[lane], b1 = br[lane + 64];
    bf16x4 o0, o1;
    o0[0] = (bf16)((v0.x - mu) * rstd * g0.x + b0.x);
    o0[1] = (bf16)((v0.y - mu) * rstd * g0.y + b0.y);
    o0[2] = (bf16)((v0.z - mu) * rstd * g0.z + b0.z);
    o0[3] = (bf16)((v0.w - mu) * rstd * g0.w + b0.w);
    o1[0] = (bf16)((v1.x - mu) * rstd * g1.x + b1.x);
    o1[1] = (bf16)((v1.y - mu) * rstd * g1.y + b1.y);
    o1[2] = (bf16)((v1.z - mu) * rstd * g1.z + b1.z);
    o1[3] = (bf16)((v1.w - mu) * rstd * g1.w + b1.w);
    *(bf16x4*)(xn + (size_t)row * 512 + lane * 4) = o0;
    *(bf16x4*)(xn + (size_t)row * 512 + 256 + lane * 4) = o1;
  }
}

// ---------------- GEMM (round-6 structure, reverted): 128x128 tile, BK=32, ring-3, vmcnt(4) ----------------
template <int MODE>
__global__ __launch_bounds__(256) void gemm_kernel(
    const bf16* __restrict__ A, const bf16* __restrict__ Bt, float* __restrict__ outF,
    bf16* __restrict__ qb, bf16* __restrict__ kb, bf16* __restrict__ vtb,
    const float* __restrict__ biasQ, const float* __restrict__ biasK,
    const float* __restrict__ biasV, const float* __restrict__ biasO) {
  __shared__ __align__(16) char smem[49152];
  bf16* sA = (bf16*)smem;            // 3 bufs x 4096 el
  bf16* sB = (bf16*)(smem + 24576);  // 3 bufs x 4096 el
  const int tid = threadIdx.x;
  const int wave = tid >> 6, lane = tid & 63;
  const int m0 = blockIdx.x * 128, n0 = blockIdx.y * 128;
  const int wm = (wave >> 1) * 64, wn = (wave & 1) * 64;
  const int lrow = lane & 15, lk = (lane >> 4) * 8;
  const int srow = lane >> 2, scol = (lane & 3) * 8;
  f32x4 acc[4][4] = {};
  auto STAGE = [&](int kt, int buf) {
    #pragma unroll
    for (int c = 0; c < 2; ++c) {
      const int ch = wave * 2 + c;
      gload16(A + (size_t)(m0 + ch * 16 + srow) * 512 + kt + scol, sA + buf * 4096 + ch * 512);
      gload16(Bt + (size_t)(n0 + ch * 16 + srow) * 512 + kt + scol, sB + buf * 4096 + ch * 512);
    }
  };
  STAGE(0, 0);
  STAGE(32, 1);
  #pragma unroll
  for (int t = 0; t < 16; ++t) {
    if (t == 15) asm volatile("s_waitcnt vmcnt(0)" ::: "memory");
    else        asm volatile("s_waitcnt vmcnt(4)" ::: "memory");
    __builtin_amdgcn_s_barrier();
    asm volatile("" ::: "memory");
    if (t < 14) STAGE((t + 2) * 32, (t + 2) % 3);
    const int buf = t % 3;
    bf16x8 af[4], bfr[4];
    #pragma unroll
    for (int mi = 0; mi < 4; ++mi)
      af[mi] = *(const bf16x8*)(sA + buf * 4096 + (wm + mi * 16 + lrow) * 32 + lk);
    #pragma unroll
    for (int ni = 0; ni < 4; ++ni)
      bfr[ni] = *(const bf16x8*)(sB + buf * 4096 + (wn + ni * 16 + lrow) * 32 + lk);
    __builtin_amdgcn_s_setprio(1);
    #pragma unroll
    for (int mi = 0; mi < 4; ++mi)
      #pragma unroll
      for (int ni = 0; ni < 4; ++ni)
        acc[mi][ni] = __builtin_amdgcn_mfma_f32_16x16x32_bf16(af[mi], bfr[ni], acc[mi][ni], 0, 0, 0);
    __builtin_amdgcn_s_setprio(0);
  }
  if (MODE == 0) {
    const int yy = blockIdx.y;
    if (yy < 8) {
      const bool isQ = (yy < 4);
      bf16* dst = isQ ? qb : kb;
      const float* bias = isQ ? biasQ : biasK;
      #pragma unroll
      for (int ni = 0; ni < 4; ++ni) {
        const int n = n0 + wn + ni * 16 + lrow;
        const int rem = n & 511;
        const int hh = rem >> 6, d = rem & 63;
        const float bv = bias[rem];
        #pragma unroll
        for (int mi = 0; mi < 4; ++mi) {
          #pragma unroll
          for (int r = 0; r < 4; ++r) {
            const int m = m0 + wm + mi * 16 + (lane >> 4) * 4 + r;
            const int bb = m >> 10, ss = m & 1023;
            float val = acc[mi][ni][r] + bv;
            if (isQ) val *= QSCL;
            dst[(((size_t)bb * 8 + hh) * 1024 + ss) * 64 + d] = (bf16)val;
          }
        }
      }
    } else {
      // V: transpose through swizzled LDS tile, then coalesced 16B stores
      const int rem0 = n0 - 1024;
      const int bb = m0 >> 10, ss0 = m0 & 1023;
      __syncthreads();
      #pragma unroll
      for (int ni = 0; ni < 4; ++ni) {
        const int n_loc = wn + ni * 16 + lrow;
        const float bv = biasV[rem0 + n_loc];
        #pragma unroll
        for (int mi = 0; mi < 4; ++mi) {
          #pragma unroll
          for (int r = 0; r < 4; ++r) {
            const int m_loc = wm + mi * 16 + (lane >> 4) * 4 + r;
            *(bf16*)(smem + n_loc * 256 + ((m_loc * 2) ^ ((n_loc & 15) << 4))) =
                (bf16)(acc[mi][ni][r] + bv);
          }
        }
      }
      __syncthreads();
      const int rr = tid >> 4, kk = tid & 15;
      #pragma unroll
      for (int p = 0; p < 8; ++p) {
        const int r = p * 16 + rr;
        const bf16x8 vv = *(const bf16x8*)(smem + r * 256 + ((kk * 16) ^ ((r & 15) << 4)));
        *(bf16x8*)(vtb + (size_t)bb * 524288 + (size_t)(rem0 + r) * 1024 + ss0 + kk * 8) = vv;
      }
    }
  } else {
    #pragma unroll
    for (int ni = 0; ni < 4; ++ni) {
      const int n = n0 + wn + ni * 16 + lrow;
      const float bias = biasO[n];
      #pragma unroll
      for (int mi = 0; mi < 4; ++mi) {
        #pragma unroll
        for (int r = 0; r < 4; ++r) {
          const int m = m0 + wm + mi * 16 + (lane >> 4) * 4 + r;
          outF[(size_t)m * 512 + n] = acc[mi][ni][r] + bias;
        }
      }
    }
  }
}

// ---------------- flash attention: swapped-QK 32x32 MFMA, KVBLK=128, raw-exp2 softmax ----------------
// 4 waves x 32 q-rows; K/V tiles (128 kv) double-buffered in LDS, 512B rows, swz = ql<<4 (bits 4-8),
// inverse swizzle pre-applied on the GLOBAL source address (global_load_lds writes linearly).
__global__ __launch_bounds__(256, 2) void attn_kernel(
    const bf16* __restrict__ qbuf, const bf16* __restrict__ kbuf,
    const bf16* __restrict__ vtbuf, bf16* __restrict__ z) {
  __shared__ __align__(16) char sK[2][16384];
  __shared__ __align__(16) char sV[2][16384];
  const int tid = threadIdx.x;
  const int wave = tid >> 6, lane = tid & 63;
  const int bh = blockIdx.x;
  const int b = bh >> 3, h = bh & 7;
  const int y = blockIdx.y;
  const int q0 = y * 128 + wave * 32;
  const int ql = lane & 31, hf = lane >> 5;
  const bf16* Q  = qbuf  + (size_t)bh * 65536;
  const bf16* K  = kbuf  + (size_t)bh * 65536;
  const bf16* Vt = vtbuf + (size_t)bh * 65536;

  bf16x8 qf[4];
  #pragma unroll
  for (int s = 0; s < 4; ++s)
    qf[s] = *(const bf16x8*)(Q + (size_t)(q0 + ql) * 64 + s * 16 + hf * 8);

  // staging precompute: dest byte p (linear) -> deswizzled global source offsets
  int kOff[4], vOff[4], dstO[4];
  #pragma unroll
  for (int cc = 0; cc < 4; ++cc) {
    const int p = cc * 4096 + tid * 16;
    const int row = p >> 9, inner = p & 511;
    const int inn = inner ^ ((row & 31) << 4);
    kOff[cc] = (row + (inn >> 7) * 32) * 128 + (inn & 127);   // K[kv][d]: kv rows of 128B
    vOff[cc] = (row + (inn >> 8) * 32) * 2048 + (inn & 255);  // Vt[d][s]: d rows of 2048B
    dstO[cc] = cc * 4096 + wave * 1024;                       // wave-uniform base (+lane*16 in HW)
  }
  const int swzr = ql << 4;
  const int rbase = ql * 512;
  const int iq = q0 + ql;
  const int thr = (iq < 823) ? 823 : ((iq == 1023) ? 1024 : iq);

  float lsum = 0.f;
  f32x16 og[2] = {};
  const int ntile = (y == 7) ? 8 : 7;

  #pragma unroll
  for (int cc = 0; cc < 4; ++cc) {
    gload16((const char*)K + kOff[cc], sK[0] + dstO[cc]);
    gload16((const char*)Vt + vOff[cc], sV[0] + dstO[cc]);
  }
  __syncthreads();

  for (int jt = 0; jt < ntile; ++jt) {
    const int j0 = jt * 128;
    const int cur = jt & 1;
    if (jt + 1 < ntile) {
      #pragma unroll
      for (int cc = 0; cc < 4; ++cc) {
        gload16((const char*)K + (size_t)(j0 + 128) * 128 + kOff[cc], sK[cur ^ 1] + dstO[cc]);
        gload16((const char*)Vt + (size_t)(j0 + 128) * 2 + vOff[cc], sV[cur ^ 1] + dstO[cc]);
      }
    }
    // ---- S^T[kv][q]: 16 MFMA ----
    f32x16 st[4] = {};
    __builtin_amdgcn_s_setprio(1);
    #pragma unroll
    for (int bb = 0; bb < 4; ++bb)
      #pragma unroll
      for (int s = 0; s < 4; ++s) {
        const bf16x8 kf = *(const bf16x8*)(sK[cur] + rbase + ((bb * 128 + s * 32 + hf * 16) ^ swzr));
        st[bb] = __builtin_amdgcn_mfma_f32_32x32x16_bf16(kf, qf[s], st[bb], 0, 0, 0);
      }
    __builtin_amdgcn_s_setprio(0);
    // ---- mask (only tiles 6,7 intersect the blocked region) ----
    if (jt >= 6) {
      #pragma unroll
      for (int bb = 0; bb < 4; ++bb)
        #pragma unroll
        for (int rg = 0; rg < 16; ++rg) {
          const int kv = j0 + bb * 32 + (rg & 3) + 8 * (rg >> 2) + 4 * hf;
          if (kv >= thr) st[bb][rg] = -1e9f;
        }
    }
    // ---- per-32-kv-block: P = exp2(S), pack, cross-half exchange, PV ----
    #pragma unroll
    for (int bb = 0; bb < 4; ++bb) {
      unsigned pk[8];
      float ps = 0.f;
      #pragma unroll
      for (int c = 0; c < 4; ++c) {
        const float p0 = exp2f(st[bb][4 * c + 0]);
        const float p1 = exp2f(st[bb][4 * c + 1]);
        const float p2 = exp2f(st[bb][4 * c + 2]);
        const float p3 = exp2f(st[bb][4 * c + 3]);
        ps += (p0 + p1) + (p2 + p3);
        pk[c * 2 + 0] = pack2bf(p0, p1);
        pk[c * 2 + 1] = pack2bf(p2, p3);
      }
      lsum += ps;
      unsigned sw[8];
      #pragma unroll
      for (int w = 0; w < 8; ++w) sw[w] = __shfl_xor(pk[w], 32);
      __builtin_amdgcn_s_setprio(1);
      #pragma unroll
      for (int tt = 0; tt < 2; ++tt) {
        union { unsigned u[4]; bf16x8 v; } fr;
        fr.u[0] = hf ? sw[(2 * tt + 1) * 2 + 0] : pk[(2 * tt) * 2 + 0];
        fr.u[1] = hf ? sw[(2 * tt + 1) * 2 + 1] : pk[(2 * tt) * 2 + 1];
        fr.u[2] = hf ? pk[(2 * tt + 1) * 2 + 0] : sw[(2 * tt) * 2 + 0];
        fr.u[3] = hf ? pk[(2 * tt + 1) * 2 + 1] : sw[(2 * tt) * 2 + 1];
        const int kstep = bb * 2 + tt;
        #pragma unroll
        for (int g = 0; g < 2; ++g) {
          const bf16x8 vf =
              *(const bf16x8*)(sV[cur] + rbase + ((g * 256 + kstep * 32 + hf * 16) ^ swzr));
          og[g] = __builtin_amdgcn_mfma_f32_32x32x16_bf16(fr.v, vf, og[g], 0, 0, 0);
        }
      }
      __builtin_amdgcn_s_setprio(0);
    }
    __syncthreads();  // drains next-tile staging (hidden under this tile's compute) + LDS protect
  }
  lsum += __shfl_xor(lsum, 32);
  const float inv = 1.f / lsum;
  #pragma unroll
  for (int rg = 0; rg < 16; ++rg) {
    const int rowq = (rg & 3) + 8 * (rg >> 2) + 4 * hf;
    const float oinv = bperm_f(rowq << 2, inv);
    const int q_abs = q0 + rowq;
    #pragma unroll
    for (int g = 0; g < 2; ++g)
      z[((size_t)b * 1024 + q_abs) * 512 + h * 64 + g * 32 + ql] = (bf16)(og[g][rg] * oinv);
  }
}

extern "C" void kernel_launch(void* const* d_in, const int* in_sizes, int n_in,
                              void* d_out, int out_size, void* d_ws, size_t ws_size,
                              hipStream_t stream) {
  const float* x  = (const float*)d_in[0];
  const float* g  = (const float*)d_in[1];
  const float* be = (const float*)d_in[2];
  const float* WQ = (const float*)d_in[3];
  const float* bq = (const float*)d_in[4];
  const float* WK = (const float*)d_in[5];
  const float* bk = (const float*)d_in[6];
  const float* WV = (const float*)d_in[7];
  const float* bv = (const float*)d_in[8];
  const float* WO = (const float*)d_in[9];
  const float* bO = (const float*)d_in[10];
  float* out = (float*)d_out;
  char* ws = (char*)d_ws;
  bf16* xn  = (bf16*)(ws);              // [8192][512] LN output, later reused as z
  bf16* Bt  = (bf16*)(ws + 8388608);    // [1536][512] packed QKV weights^T
  bf16* WOt = (bf16*)(ws + 9961472);    // [512][512]  WO^T
  bf16* qb  = (bf16*)(ws + 10485760);   // [8][8][1024][64]
  bf16* kb  = (bf16*)(ws + 18874368);   // [8][8][1024][64]
  bf16* vtb = (bf16*)(ws + 27262976);   // [8][8][64][1024]
  prep_kernel<<<3072, 256, 0, stream>>>(x, g, be, WQ, WK, WV, WO, xn, Bt, WOt);
  gemm_kernel<0><<<dim3(64, 12), 256, 0, stream>>>(xn, Bt, nullptr, qb, kb, vtb, bq, bk, bv, nullptr);
  attn_kernel<<<dim3(64, 8), 256, 0, stream>>>(qb, kb, vtb, xn /* reuse as z */);
  gemm_kernel<1><<<dim3(64, 4), 256, 0, stream>>>(xn, WOt, out, nullptr, nullptr, nullptr,
                                                  nullptr, nullptr, nullptr, bO);
}